// Round 13
// baseline (1108.138 us; speedup 1.0000x reference)
//
#include <hip/hip_runtime.h>

using u16 = unsigned short;
using u32 = unsigned int;

typedef __attribute__((ext_vector_type(8))) __bf16 bf16x8;
typedef __attribute__((ext_vector_type(4))) float f32x4;
typedef __attribute__((ext_vector_type(16))) float f32x16;

__device__ __forceinline__ u16 f2bf(float f) {
  __bf16 h = (__bf16)f;
  return __builtin_bit_cast(u16, h);
}
__device__ __forceinline__ u32 pk2(float a, float b) {
  return (u32)f2bf(a) | ((u32)f2bf(b) << 16);
}
__device__ __forceinline__ float bf2f(u16 h) {
  return __uint_as_float(((u32)h) << 16);
}
__device__ __forceinline__ void gload16(const u16* g, u16* l) {
  __builtin_amdgcn_global_load_lds((const __attribute__((address_space(1))) void*)g,
                                   (__attribute__((address_space(3))) void*)l, 16, 0, 0);
}
__device__ __forceinline__ f32x4 mfma_bf16(bf16x8 a, bf16x8 b, f32x4 c) {
  return __builtin_amdgcn_mfma_f32_16x16x32_bf16(a, b, c, 0, 0, 0);
}
__device__ __forceinline__ f32x16 mfma32(bf16x8 a, bf16x8 b, f32x16 c) {
  return __builtin_amdgcn_mfma_f32_32x32x16_bf16(a, b, c, 0, 0, 0);
}

// ---------------- fp32 -> bf16 convert (single job) ----------------
__global__ __launch_bounds__(256) void cvt_bf16(const float* __restrict__ in,
                                                u16* __restrict__ out, int n8) {
  int i = blockIdx.x * 256 + threadIdx.x;
  int stride = gridDim.x * 256;
  for (; i < n8; i += stride) {
    float4 a = ((const float4*)in)[(size_t)i * 2];
    float4 b = ((const float4*)in)[(size_t)i * 2 + 1];
    ((uint4*)out)[i] = make_uint4(pk2(a.x, a.y), pk2(a.z, a.w), pk2(b.x, b.y), pk2(b.z, b.w));
  }
}

// ---------------- fp32 -> bf16 convert, all 7 weights in one dispatch ----------------
struct CvtJobs {
  const float* in[7];
  u16* out[7];
  int n8[7];
};
__global__ __launch_bounds__(256) void cvt_all(CvtJobs c) {
  const int stride = gridDim.x * 256;
  const int base = blockIdx.x * 256 + threadIdx.x;
#pragma unroll
  for (int j = 0; j < 7; ++j) {
    const float* in = c.in[j];
    u16* out = c.out[j];
    const int n8 = c.n8[j];
    for (int i = base; i < n8; i += stride) {
      float4 a = ((const float4*)in)[(size_t)i * 2];
      float4 b = ((const float4*)in)[(size_t)i * 2 + 1];
      ((uint4*)out)[i] = make_uint4(pk2(a.x, a.y), pk2(a.z, a.w), pk2(b.x, b.y), pk2(b.z, b.w));
    }
  }
}

// ---------------- RMSNorm (H=2048), fp32 in -> bf16 out ----------------
__global__ __launch_bounds__(256) void rmsnorm_bf16(const float* __restrict__ x,
                                                    const float* __restrict__ g,
                                                    u16* __restrict__ o) {
  const int row = blockIdx.x;
  const int tid = threadIdx.x;
  const float4* xr = (const float4*)(x + (size_t)row * 2048);
  float4 a = xr[tid * 2], b = xr[tid * 2 + 1];
  float s = a.x * a.x + a.y * a.y + a.z * a.z + a.w * a.w +
            b.x * b.x + b.y * b.y + b.z * b.z + b.w * b.w;
#pragma unroll
  for (int off = 1; off < 64; off <<= 1) s += __shfl_xor(s, off);
  __shared__ float red[4];
  if ((tid & 63) == 0) red[tid >> 6] = s;
  __syncthreads();
  s = red[0] + red[1] + red[2] + red[3];
  const float r = rsqrtf(s * (1.0f / 2048.0f) + 1.1920929e-07f);
  const float4* gr = (const float4*)g;
  float4 ga = gr[tid * 2], gb = gr[tid * 2 + 1];
  ((uint4*)(o + (size_t)row * 2048))[tid] =
      make_uint4(pk2(a.x * r * ga.x, a.y * r * ga.y), pk2(a.z * r * ga.z, a.w * r * ga.w),
                 pk2(b.x * r * gb.x, b.y * r * gb.y), pk2(b.z * r * gb.z, b.w * r * gb.w));
}

// ========== fused gate+up GEMM, 32x32x16 MFMA, FRAG-MAJOR LDS (lane-linear reads) ==========
// Out = silu(A@Wg^T) * (A@Wu^T), bf16. Same phases / vmcnt(4) accounting as R11/R12.
// LDS layout per slot: addr(widx,row) = (widx*R + row)*8 u16, widx = kq*2+lh.
// Frag read: lane(l31,lh) -> slot + (lh*R + wrow + l31)*8 + kq*(2R*8) + mb*256
//   => lanes 0-31 / 32-63 each read CONTIGUOUS 512B runs: conflict-free by construction.
// Staging: thread t fetches global row (t mod R), k-window (t div R) -> linear LDS dest.
__global__ __launch_bounds__(512, 1) void gemmGU(const u16* __restrict__ A,
                                                 const u16* __restrict__ Bg,
                                                 const u16* __restrict__ Bu,
                                                 u16* __restrict__ Out,
                                                 int M, int N, int K) {
  alignas(16) __shared__ u16 lds[2 * 32768];
  const int tid = threadIdx.x;
  const int w = tid >> 6, lane = tid & 63;
  const int l31 = lane & 31, lh = lane >> 5;
  // 2-D region-per-XCD swizzle
  const int nbm = M >> 8, nbx = N >> 7;
  const int RM = nbm >> 1, RN = nbx >> 2;
  const int xcd = blockIdx.x & 7, bidx = blockIdx.x >> 3;
  const int bm = ((xcd >> 2) * RM + bidx / RN) << 8;
  const int bn = ((xcd & 3) * RN + bidx % RN) << 7;
  const int wm = w >> 1, wn = w & 1;

  // frag-major read bases (u16 offsets within slot)
  const int aBase = (lh * 256 + wm * 64 + l31) * 8;  // + kq*4096 + mb*256
  const int bBase = (lh * 128 + wn * 64 + l31) * 8;  // + kq*2048 + nb*256

  // staging source: A rows 256 (2 windows/call-set), B rows 128 (4 windows)
  const int rowA = tid & 255, wA = tid >> 8;
  const int rowB = tid & 127, wB = tid >> 7;
  const u16* Ab = A + (size_t)(bm + rowA) * K + wA * 8;
  const u16* Bgb = Bg + (size_t)(bn + rowB) * K + wB * 8;
  const u16* Bub = Bu + (size_t)(bn + rowB) * K + wB * 8;

  f32x16 gacc[2][2] = {}, uacc[2][2] = {};
  bf16x8 af[2][2], bf[2][2];

#define AOFF(par, kh) ((par)*32768 + (kh)*8192)
#define BGOFF(par, kh) ((par)*32768 + 16384 + (kh)*4096)
#define BUOFF(par, kh) ((par)*32768 + 24576 + (kh)*4096)
#define STG_A(par, kh, kt)                                                  \
  {                                                                         \
    gload16(Ab + (kt) + (kh)*32, &lds[AOFF(par, kh) + tid * 8]);            \
    gload16(Ab + (kt) + (kh)*32 + 16, &lds[AOFF(par, kh) + 4096 + tid * 8]); \
  }
#define STG_B(par, kh, kt)                                                  \
  {                                                                         \
    gload16(Bgb + (kt) + (kh)*32, &lds[BGOFF(par, kh) + tid * 8]);          \
    gload16(Bub + (kt) + (kh)*32, &lds[BUOFF(par, kh) + tid * 8]);          \
  }
#define PHASE_SYNC()                                   \
  __builtin_amdgcn_s_barrier();                        \
  asm volatile("s_waitcnt lgkmcnt(0)" ::: "memory");   \
  __builtin_amdgcn_sched_barrier(0);
#define LD_A(slot)                                                             \
  _Pragma("unroll") for (int mb = 0; mb < 2; ++mb)                             \
      _Pragma("unroll") for (int kq = 0; kq < 2; ++kq)                         \
          af[mb][kq] = *(const bf16x8*)(&lds[(slot) + aBase + kq * 4096 + mb * 256]);
#define LD_B(slot)                                                             \
  _Pragma("unroll") for (int nb = 0; nb < 2; ++nb)                             \
      _Pragma("unroll") for (int kq = 0; kq < 2; ++kq)                         \
          bf[nb][kq] = *(const bf16x8*)(&lds[(slot) + bBase + kq * 2048 + nb * 256]);
#define MFMA8(ACC)                                                             \
  __builtin_amdgcn_s_setprio(1);                                               \
  _Pragma("unroll") for (int kq = 0; kq < 2; ++kq)                             \
      _Pragma("unroll") for (int mb = 0; mb < 2; ++mb)                         \
          _Pragma("unroll") for (int nb = 0; nb < 2; ++nb)                     \
              ACC[mb][nb] = mfma32(af[mb][kq], bf[nb][kq], ACC[mb][nb]);       \
  __builtin_amdgcn_s_setprio(0);

  STG_A(0, 0, 0); STG_B(0, 0, 0); STG_A(0, 1, 0); STG_B(0, 1, 0);
  asm volatile("s_waitcnt vmcnt(0)" ::: "memory");
  __builtin_amdgcn_s_barrier();

  const int NT = K >> 6;
  for (int t = 0; t < NT; ++t) {
    const int par = t & 1, np = par ^ 1;
    const int ktn = (t + 1) << 6;
    const bool pre = (t + 1 < NT);

    // P0: kh0, gate
    LD_B(BGOFF(par, 0));
    LD_A(AOFF(par, 0));
    if (pre) STG_A(np, 0, ktn);
    PHASE_SYNC();
    MFMA8(gacc);

    // P1: kh0, up (af reused)
    LD_B(BUOFF(par, 0));
    if (pre) STG_B(np, 0, ktn);
    if (pre) { asm volatile("s_waitcnt vmcnt(4)" ::: "memory"); }
    else     { asm volatile("s_waitcnt vmcnt(0)" ::: "memory"); }
    PHASE_SYNC();
    MFMA8(uacc);

    // P2: kh1, gate
    LD_B(BGOFF(par, 1));
    LD_A(AOFF(par, 1));
    if (pre) STG_A(np, 1, ktn);
    PHASE_SYNC();
    MFMA8(gacc);

    // P3: kh1, up
    LD_B(BUOFF(par, 1));
    if (pre) STG_B(np, 1, ktn);
    if (pre) { asm volatile("s_waitcnt vmcnt(4)" ::: "memory"); }
    PHASE_SYNC();
    MFMA8(uacc);
  }
#undef AOFF
#undef BGOFF
#undef BUOFF
#undef STG_A
#undef STG_B
#undef PHASE_SYNC
#undef LD_A
#undef LD_B
#undef MFMA8

#pragma unroll
  for (int mb = 0; mb < 2; ++mb)
#pragma unroll
    for (int nb = 0; nb < 2; ++nb) {
      const int gc = bn + wn * 64 + nb * 32 + l31;
#pragma unroll
      for (int reg = 0; reg < 16; ++reg) {
        const int gr = bm + wm * 64 + mb * 32 + (reg & 3) + 8 * (reg >> 2) + 4 * lh;
        float g = gacc[mb][nb][reg];
        float s = g / (1.f + __expf(-g));
        Out[(size_t)gr * N + gc] = f2bf(s * uacc[mb][nb][reg]);
      }
    }
}

// ========== 3-deep 256x128 GEMM, 32x32x16 MFMA, FRAG-MAJOR LDS (QKV / O / down) ==========
template <int EPI>
__global__ __launch_bounds__(512, 1) void gemm3b(const u16* __restrict__ A,
                                                 const u16* __restrict__ B,
                                                 u16* Cb, float* Cf,
                                                 const float* __restrict__ Res,
                                                 int M, int N, int K, int lda) {
  constexpr int BUF = 24576;
  alignas(16) __shared__ u16 lds[3 * BUF];
  const int tid = threadIdx.x;
  const int w = tid >> 6, lane = tid & 63;
  const int l31 = lane & 31, lh = lane >> 5;

  const int nbm = M >> 8, nbx = N >> 7;
  const int RM = nbm >> 1, RN = nbx >> 2;
  const int xcd = blockIdx.x & 7, idx = blockIdx.x >> 3;
  const int bm = ((xcd >> 2) * RM + idx / RN) << 8;
  const int bn = ((xcd & 3) * RN + idx % RN) << 7;

  const int wm = w >> 1, wn = w & 1;
  // frag-major bases: A buf = 8 windows x 256 rows; B buf = 8 windows x 128 rows
  const int aBase = (lh * 256 + wm * 64 + l31) * 8;  // + kq*4096 + mb*256
  const int bBase = (lh * 128 + wn * 64 + l31) * 8;  // + kq*2048 + nb*256

  const int rowA = tid & 255, wA = tid >> 8;
  const int rowB = tid & 127, wB = tid >> 7;
  const u16* Ag = A + (size_t)(bm + rowA) * lda + wA * 8;
  const u16* Bp = B + (size_t)(bn + rowB) * K + wB * 8;

  f32x16 acc[2][2] = {};

#define STG(b, kt)                                                                  \
  {                                                                                 \
    _Pragma("unroll") for (int c = 0; c < 4; ++c)                                   \
        gload16(Ag + (kt) + c * 16, &lds[(b)*BUF + c * 4096 + tid * 8]);            \
    _Pragma("unroll") for (int c = 0; c < 2; ++c)                                   \
        gload16(Bp + (kt) + c * 32, &lds[(b)*BUF + 16384 + c * 4096 + tid * 8]);    \
  }

  const int NT = K >> 6;
  STG(0, 0);
  STG(1, 64);

  int cur = 0;
  for (int T = 0; T < NT; ++T) {
    if (T + 1 < NT) {
      asm volatile("s_waitcnt vmcnt(6)" ::: "memory");
    } else {
      asm volatile("s_waitcnt vmcnt(0)" ::: "memory");
    }
    __builtin_amdgcn_s_barrier();
    __builtin_amdgcn_sched_barrier(0);

    const u16* LA = &lds[cur * BUF];
    const u16* LB = LA + 16384;
    bf16x8 af[2][4], bf[2][4];
#pragma unroll
    for (int mb = 0; mb < 2; ++mb)
#pragma unroll
      for (int kq = 0; kq < 4; ++kq)
        af[mb][kq] = *(const bf16x8*)(LA + aBase + kq * 4096 + mb * 256);
#pragma unroll
    for (int nb = 0; nb < 2; ++nb)
#pragma unroll
      for (int kq = 0; kq < 4; ++kq)
        bf[nb][kq] = *(const bf16x8*)(LB + bBase + kq * 2048 + nb * 256);
    if (T + 2 < NT) {
      const int nb2 = (cur + 2) % 3;
      STG(nb2, (T + 2) << 6);
    }
    __builtin_amdgcn_s_setprio(1);
#pragma unroll
    for (int kq = 0; kq < 4; ++kq)
#pragma unroll
      for (int mb = 0; mb < 2; ++mb)
#pragma unroll
        for (int nb = 0; nb < 2; ++nb)
          acc[mb][nb] = mfma32(af[mb][kq], bf[nb][kq], acc[mb][nb]);
    __builtin_amdgcn_s_setprio(0);
    cur = (cur + 1) % 3;
  }
#undef STG

#pragma unroll
  for (int mb = 0; mb < 2; ++mb)
#pragma unroll
    for (int nb = 0; nb < 2; ++nb) {
      const int gc = bn + wn * 64 + nb * 32 + l31;
#pragma unroll
      for (int reg = 0; reg < 16; ++reg) {
        const int gr = bm + wm * 64 + mb * 32 + (reg & 3) + 8 * (reg >> 2) + 4 * lh;
        const size_t idx2 = (size_t)gr * N + gc;
        if constexpr (EPI == 1) {
          Cf[idx2] = Res[idx2] + acc[mb][nb][reg];
        } else if constexpr (EPI == 2) {
          float g = bf2f(Cb[idx2]);
          float s = g / (1.f + __expf(-g));
          Cb[idx2] = f2bf(s * acc[mb][nb][reg]);
        } else {
          Cb[idx2] = f2bf(acc[mb][nb][reg]);
        }
      }
    }
}

// ---------------- old 128^2 GEMM (fallback tier), fp32 B on the fly ----------------
template <int EPI>
__global__ __launch_bounds__(256) void gemm_bt(const u16* __restrict__ A,
                                               const float* __restrict__ B,
                                               u16* Cb, float* Cf, const float* Res,
                                               int M, int N, int K) {
  alignas(16) __shared__ u16 As[128 * 32];
  alignas(16) __shared__ u16 Bs[128 * 32];
  const int tid = threadIdx.x;
  const int w = tid >> 6, lane = tid & 63;
  const int lo = lane & 15, hi = lane >> 4;
  const int bm = blockIdx.y * 128, bn = blockIdx.x * 128;
  const int wr = (w >> 1) * 64, wc = (w & 1) * 64;
  f32x4 acc[4][4] = {};
  const int r0 = tid >> 2, kc0 = (tid & 3) * 8;
  const u16* a0 = A + (size_t)(bm + r0) * K + kc0;
  const u16* a1 = A + (size_t)(bm + 64 + r0) * K + kc0;
  const float* b0 = B + (size_t)(bn + r0) * K + kc0;
  const float* b1 = B + (size_t)(bn + 64 + r0) * K + kc0;
  u16* asd0 = &As[(size_t)tid * 8];
  u16* asd1 = &As[(size_t)(tid + 256) * 8];
  u16* bsd0 = &Bs[(size_t)tid * 8];
  u16* bsd1 = &Bs[(size_t)(tid + 256) * 8];
  for (int kt = 0; kt < K; kt += 32) {
    gload16(a0 + kt, asd0);
    gload16(a1 + kt, asd1);
    float4 x0 = *(const float4*)(b0 + kt);
    float4 x1 = *(const float4*)(b0 + kt + 4);
    float4 y0 = *(const float4*)(b1 + kt);
    float4 y1 = *(const float4*)(b1 + kt + 4);
    *(uint4*)bsd0 = make_uint4(pk2(x0.x, x0.y), pk2(x0.z, x0.w), pk2(x1.x, x1.y), pk2(x1.z, x1.w));
    *(uint4*)bsd1 = make_uint4(pk2(y0.x, y0.y), pk2(y0.z, y0.w), pk2(y1.x, y1.y), pk2(y1.z, y1.w));
    __syncthreads();
    bf16x8 af[4], bfr[4];
#pragma unroll
    for (int i = 0; i < 4; ++i) {
      af[i] = *(const bf16x8*)(&As[(wr + i * 16 + lo) * 32 + hi * 8]);
      bfr[i] = *(const bf16x8*)(&Bs[(wc + i * 16 + lo) * 32 + hi * 8]);
    }
#pragma unroll
    for (int i = 0; i < 4; ++i)
#pragma unroll
      for (int j = 0; j < 4; ++j) acc[i][j] = mfma_bf16(af[i], bfr[j], acc[i][j]);
    __syncthreads();
  }
#pragma unroll
  for (int i = 0; i < 4; ++i) {
    const int gr = bm + wr + i * 16 + hi * 4;
#pragma unroll
    for (int j = 0; j < 4; ++j) {
      const int gc = bn + wc + j * 16 + lo;
#pragma unroll
      for (int r = 0; r < 4; ++r) {
        const size_t idx = (size_t)(gr + r) * N + gc;
        if constexpr (EPI == 1) {
          Cf[idx] = Res[idx] + acc[i][j][r];
        } else if constexpr (EPI == 2) {
          float g = bf2f(Cb[idx]);
          float s = g / (1.f + __expf(-g));
          Cb[idx] = f2bf(s * acc[i][j][r]);
        } else {
          Cb[idx] = f2bf(acc[i][j][r]);
        }
      }
    }
  }
}

// ---------------- V transpose: v rows (stride ldv) -> vt[bh*128+d][S] ----------------
__global__ __launch_bounds__(256) void transpose_v(const u16* __restrict__ v,
                                                   u16* __restrict__ vt, int ldv) {
  __shared__ u16 t[32][33];
  const int bh = blockIdx.z, b = bh >> 4, h = bh & 15;
  const int s0 = blockIdx.x * 32, d0 = blockIdx.y * 32;
  const int tx = threadIdx.x, ty = threadIdx.y;
#pragma unroll
  for (int i = 0; i < 4; ++i)
    t[ty + i * 8][tx] = v[(size_t)(b * 2048 + s0 + ty + i * 8) * ldv + h * 128 + d0 + tx];
  __syncthreads();
#pragma unroll
  for (int i = 0; i < 4; ++i)
    vt[(size_t)(bh * 128 + d0 + ty + i * 8) * 2048 + s0 + tx] = t[tx][ty + i * 8];
}

// ---------------- flash attention fwd: 512 thr, 128 q-rows/block, NO-MAX softmax ----------------
__global__ __launch_bounds__(512) void attn_fwd3(const u16* __restrict__ q,
                                                 const u16* __restrict__ k,
                                                 const u16* __restrict__ vt,
                                                 u16* o, int ldq) {
  constexpr int S = 2048;
  alignas(16) __shared__ u16 Ks[2][64 * 128];
  alignas(16) __shared__ u16 Vs[2][128 * 64];
  alignas(16) __shared__ u16 plds[8][16 * 68];
  const int bh = blockIdx.y, b = bh >> 4, h = bh & 15;
  const int tid = threadIdx.x, w = tid >> 6, lane = tid & 63;
  const int lo = lane & 15, hi = lane >> 4;
  const int qr = blockIdx.x * 128 + w * 16;
  u16* pl = &plds[w][0];

  bf16x8 qf[4];
  const u16* qb = q + (size_t)(b * S + qr + lo) * ldq + h * 128 + hi * 8;
#pragma unroll
  for (int ks = 0; ks < 4; ++ks) qf[ks] = *(const bf16x8*)(qb + ks * 32);

  f32x4 oacc[8] = {};
  f32x4 lp = {0.f, 0.f, 0.f, 0.f};

  const u16* kb = k + (size_t)(b * S) * ldq + h * 128;
  const u16* vb = vt + (size_t)bh * 128 * S;

  const int kcs = ((tid & 15) ^ ((tid >> 4) & 7)) * 8;
  const int vcs = ((tid & 7) ^ ((tid >> 3) & 7)) * 8;
  const u16* kgs = kb + (size_t)(tid >> 4) * ldq + kcs;
  const u16* vgs = vb + (size_t)(tid >> 3) * S + vcs;

  int cur = 0;
#pragma unroll
  for (int c = 0; c < 2; ++c) gload16(kgs + (size_t)(c * 32) * ldq, &Ks[0][c * 4096 + tid * 8]);
#pragma unroll
  for (int c = 0; c < 2; ++c) gload16(vgs + (size_t)(c * 64) * S, &Vs[0][c * 4096 + tid * 8]);
  __syncthreads();

  const int swq = (lo & 7) << 4;
  constexpr float SCL = 0.12752956f;  // (1/sqrt(128)) * log2(e)

  for (int kv = 0; kv < S; kv += 64) {
    if (kv + 64 < S) {
      const int nb = cur ^ 1;
#pragma unroll
      for (int c = 0; c < 2; ++c)
        gload16(kgs + (size_t)(kv + 64 + c * 32) * ldq, &Ks[nb][c * 4096 + tid * 8]);
#pragma unroll
      for (int c = 0; c < 2; ++c)
        gload16(vgs + (size_t)(c * 64) * S + kv + 64, &Vs[nb][c * 4096 + tid * 8]);
    }
    const u16* Kc = &Ks[cur][0];
    const u16* Vc = &Vs[cur][0];

    f32x4 sacc[4] = {};
    __builtin_amdgcn_s_setprio(1);
#pragma unroll
    for (int ks = 0; ks < 4; ++ks)
#pragma unroll
      for (int n = 0; n < 4; ++n) {
        bf16x8 kf = *(const bf16x8*)(Kc + (n * 16 + lo) * 128 + (((ks * 64 + hi * 16) ^ swq) >> 1));
        sacc[n] = mfma_bf16(qf[ks], kf, sacc[n]);
      }
    __builtin_amdgcn_s_setprio(0);

    f32x4 p[4];
#pragma unroll
    for (int n = 0; n < 4; ++n)
#pragma unroll
      for (int r = 0; r < 4; ++r) p[n][r] = exp2f(sacc[n][r] * SCL);
#pragma unroll
    for (int r = 0; r < 4; ++r)
      lp[r] += (p[0][r] + p[1][r]) + (p[2][r] + p[3][r]);

#pragma unroll
    for (int n = 0; n < 4; ++n)
#pragma unroll
      for (int r = 0; r < 4; ++r)
        pl[(hi * 4 + r) * 68 + n * 16 + lo] = f2bf(p[n][r]);
    asm volatile("s_waitcnt lgkmcnt(0)" ::: "memory");
    bf16x8 pf0 = *(const bf16x8*)(pl + lo * 68 + hi * 8);
    bf16x8 pf1 = *(const bf16x8*)(pl + lo * 68 + 32 + hi * 8);

    __builtin_amdgcn_s_setprio(1);
#pragma unroll
    for (int f = 0; f < 8; ++f) {
      const int row = f * 16 + lo;
      bf16x8 vf0 = *(const bf16x8*)(Vc + row * 64 + (((hi * 16) ^ swq) >> 1));
      bf16x8 vf1 = *(const bf16x8*)(Vc + row * 64 + (((64 + hi * 16) ^ swq) >> 1));
      oacc[f] = mfma_bf16(pf0, vf0, oacc[f]);
      oacc[f] = mfma_bf16(pf1, vf1, oacc[f]);
    }
    __builtin_amdgcn_s_setprio(0);

    __syncthreads();
    cur ^= 1;
  }

  float l[4];
#pragma unroll
  for (int r = 0; r < 4; ++r) l[r] = lp[r];
#pragma unroll
  for (int off = 1; off < 16; off <<= 1)
#pragma unroll
    for (int r = 0; r < 4; ++r) l[r] += __shfl_xor(l[r], off);

  u16* ob = o + (size_t)(b * S + qr) * ldq + h * 128;
#pragma unroll
  for (int f = 0; f < 8; ++f)
#pragma unroll
    for (int r = 0; r < 4; ++r)
      ob[(size_t)(hi * 4 + r) * ldq + f * 16 + lo] = f2bf(oacc[f][r] / l[r]);
}

// ---------------- host ----------------
extern "C" void kernel_launch(void* const* d_in, const int* in_sizes, int n_in,
                              void* d_out, int out_size, void* d_ws, size_t ws_size,
                              hipStream_t stream) {
  constexpr int B = 2, S = 2048, H = 2048, NH = 16, I = 8192;
  constexpr int M = B * S;  // 4096

  const float* hs = (const float*)d_in[0];
  const float* Wq = (const float*)d_in[1];
  const float* Wk = (const float*)d_in[2];
  const float* Wv = (const float*)d_in[3];
  const float* Wo = (const float*)d_in[4];
  const float* Wg = (const float*)d_in[5];
  const float* Wu = (const float*)d_in[6];
  const float* Wd = (const float*)d_in[7];
  const float* g_in = (const float*)d_in[8];
  const float* g_post = (const float*)d_in[9];
  float* out = (float*)d_out;

  constexpr size_t SZ_HH = (size_t)H * H * 2;   // 8 MiB
  constexpr size_t SZ_IH = (size_t)I * H * 2;   // 32 MiB
  constexpr size_t SZ_MH = (size_t)M * H * 2;   // 16 MiB
  constexpr size_t NEED_ALL = 5 * SZ_MH + 3 * SZ_HH + SZ_HH + 3 * SZ_IH;  // 208 MiB
  constexpr size_t NEED_FUSED = SZ_MH + 3 * SZ_MH + SZ_MH + 2 * SZ_IH;    // 144 MiB
  constexpr size_t NEED_BASE = SZ_MH + 3 * SZ_MH + SZ_MH + SZ_IH;         // 112 MiB

  if (ws_size >= NEED_ALL) {
    char* p = (char*)d_ws;
    u16* x_b = (u16*)p;    p += SZ_MH;      // [4096][2048]
    u16* qkv_b = (u16*)p;  p += 3 * SZ_MH;  // [4096][6144]
    u16* vt_b = (u16*)p;   p += SZ_MH;      // [B*NH*128][2048]
    u16* wqkv = (u16*)p;   p += 3 * SZ_HH;  // [6144][2048]
    u16* wo_b = (u16*)p;   p += SZ_HH;
    u16* wg_b = (u16*)p;   p += SZ_IH;
    u16* wu_b = (u16*)p;   p += SZ_IH;
    u16* wd_b = (u16*)p;   p += SZ_IH;
    u16* gate_b = qkv_b;                    // [4096][8192] overlay after attn

    rmsnorm_bf16<<<M, 256, 0, stream>>>(hs, g_in, x_b);

    CvtJobs cj;
    cj.in[0] = Wq;  cj.out[0] = wqkv;                     cj.n8[0] = H * H / 8;
    cj.in[1] = Wk;  cj.out[1] = wqkv + (size_t)H * H;     cj.n8[1] = H * H / 8;
    cj.in[2] = Wv;  cj.out[2] = wqkv + (size_t)2 * H * H; cj.n8[2] = H * H / 8;
    cj.in[3] = Wo;  cj.out[3] = wo_b;                     cj.n8[3] = H * H / 8;
    cj.in[4] = Wg;  cj.out[4] = wg_b;                     cj.n8[4] = I * H / 8;
    cj.in[5] = Wu;  cj.out[5] = wu_b;                     cj.n8[5] = I * H / 8;
    cj.in[6] = Wd;  cj.out[6] = wd_b;                     cj.n8[6] = I * H / 8;
    cvt_all<<<2048, 256, 0, stream>>>(cj);

    gemm3b<0><<<(M / 256) * (3 * H / 128), 512, 0, stream>>>(
        x_b, wqkv, qkv_b, nullptr, nullptr, M, 3 * H, H, H);

    transpose_v<<<dim3(S / 32, 128 / 32, B * NH), dim3(32, 8), 0, stream>>>(
        qkv_b + 2 * H, vt_b, 3 * H);
    attn_fwd3<<<dim3(S / 128, B * NH), 512, 0, stream>>>(qkv_b, qkv_b + H, vt_b, qkv_b, 3 * H);

    gemm3b<1><<<(M / 256) * (H / 128), 512, 0, stream>>>(
        qkv_b, wo_b, nullptr, out, hs, M, H, H, 3 * H);

    rmsnorm_bf16<<<M, 256, 0, stream>>>(out, g_post, x_b);

    gemmGU<<<(M / 256) * (I / 128), 512, 0, stream>>>(x_b, wg_b, wu_b, gate_b, M, I, H);

    gemm3b<1><<<(M / 256) * (H / 128), 512, 0, stream>>>(
        gate_b, wd_b, nullptr, out, out, M, H, I, I);
    return;
  }

  if (ws_size >= NEED_BASE) {
    char* p = (char*)d_ws;
    u16* x_b = (u16*)p;    p += SZ_MH;
    u16* qkv_b = (u16*)p;  p += 3 * SZ_MH;
    u16* vt_b = (u16*)p;   p += SZ_MH;
    u16* wsc = (u16*)p;    p += SZ_IH;
    u16* gate_b = qkv_b;
    const bool fused = ws_size >= NEED_FUSED;
    u16* wu_b = fused ? (u16*)p : nullptr;

    rmsnorm_bf16<<<M, 256, 0, stream>>>(hs, g_in, x_b);

    cvt_bf16<<<1024, 256, 0, stream>>>(Wq, wsc, H * H / 8);
    cvt_bf16<<<1024, 256, 0, stream>>>(Wk, wsc + (size_t)H * H, H * H / 8);
    cvt_bf16<<<1024, 256, 0, stream>>>(Wv, wsc + (size_t)2 * H * H, H * H / 8);
    gemm3b<0><<<(M / 256) * (3 * H / 128), 512, 0, stream>>>(
        x_b, wsc, qkv_b, nullptr, nullptr, M, 3 * H, H, H);

    transpose_v<<<dim3(S / 32, 128 / 32, B * NH), dim3(32, 8), 0, stream>>>(
        qkv_b + 2 * H, vt_b, 3 * H);
    attn_fwd3<<<dim3(S / 128, B * NH), 512, 0, stream>>>(qkv_b, qkv_b + H, vt_b, qkv_b, 3 * H);

    cvt_bf16<<<1024, 256, 0, stream>>>(Wo, wsc, H * H / 8);
    gemm3b<1><<<(M / 256) * (H / 128), 512, 0, stream>>>(
        qkv_b, wsc, nullptr, out, hs, M, H, H, 3 * H);

    rmsnorm_bf16<<<M, 256, 0, stream>>>(out, g_post, x_b);

    if (fused) {
      cvt_bf16<<<1024, 256, 0, stream>>>(Wg, wsc, I * H / 8);
      cvt_bf16<<<1024, 256, 0, stream>>>(Wu, wu_b, I * H / 8);
      gemmGU<<<(M / 256) * (I / 128), 512, 0, stream>>>(x_b, wsc, wu_b, gate_b, M, I, H);
    } else {
      cvt_bf16<<<1024, 256, 0, stream>>>(Wg, wsc, I * H / 8);
      gemm3b<0><<<(M / 256) * (I / 128), 512, 0, stream>>>(
          x_b, wsc, gate_b, nullptr, nullptr, M, I, H, H);
      cvt_bf16<<<1024, 256, 0, stream>>>(Wu, wsc, I * H / 8);
      gemm3b<2><<<(M / 256) * (I / 128), 512, 0, stream>>>(
          x_b, wsc, gate_b, nullptr, nullptr, M, I, H, H);
    }
    cvt_bf16<<<1024, 256, 0, stream>>>(Wd, wsc, I * H / 8);
    gemm3b<1><<<(M / 256) * (H / 128), 512, 0, stream>>>(
        gate_b, wsc, nullptr, out, out, M, H, I, I);
    return;
  }

  // ---------- fallback tier: old 128^2 path, fp32 B on the fly ----------
  constexpr int MC = 2048;
  char* p = (char*)d_ws;
  u16* x_b = (u16*)p;   p += SZ_MH;
  u16* q_b = (u16*)p;   p += SZ_MH;
  u16* k_b = (u16*)p;   p += SZ_MH;
  u16* v_b = (u16*)p;   p += SZ_MH;
  u16* vt_b = (u16*)p;  p += SZ_MH;
  u16* g_mlp = k_b;

  rmsnorm_bf16<<<M, 256, 0, stream>>>(hs, g_in, x_b);
  const dim3 gHH(H / 128, M / 128);
  gemm_bt<0><<<gHH, 256, 0, stream>>>(x_b, Wq, q_b, nullptr, nullptr, M, H, H);
  gemm_bt<0><<<gHH, 256, 0, stream>>>(x_b, Wk, k_b, nullptr, nullptr, M, H, H);
  gemm_bt<0><<<gHH, 256, 0, stream>>>(x_b, Wv, v_b, nullptr, nullptr, M, H, H);
  transpose_v<<<dim3(S / 32, 128 / 32, B * NH), dim3(32, 8), 0, stream>>>(v_b, vt_b, H);
  attn_fwd3<<<dim3(S / 128, B * NH), 512, 0, stream>>>(q_b, k_b, vt_b, q_b, H);
  gemm_bt<1><<<gHH, 256, 0, stream>>>(q_b, Wo, nullptr, out, hs, M, H, H);
  rmsnorm_bf16<<<M, 256, 0, stream>>>(out, g_post, x_b);
  const dim3 gIH(I / 128, MC / 128), gHI(H / 128, MC / 128);
  for (int mc = 0; mc < M / MC; ++mc) {
    const u16* xc = x_b + (size_t)mc * MC * H;
    float* oc = out + (size_t)mc * MC * H;
    gemm_bt<0><<<gIH, 256, 0, stream>>>(xc, Wg, g_mlp, nullptr, nullptr, MC, I, H);
    gemm_bt<2><<<gIH, 256, 0, stream>>>(xc, Wu, g_mlp, nullptr, nullptr, MC, I, H);
    gemm_bt<1><<<gHI, 256, 0, stream>>>(g_mlp, Wd, nullptr, oc, oc, MC, H, I);
  }
}

// Round 14
// 768.868 us; speedup vs baseline: 1.4413x; 1.4413x over previous
//
#include <hip/hip_runtime.h>

using u16 = unsigned short;
using u32 = unsigned int;

typedef __attribute__((ext_vector_type(8))) __bf16 bf16x8;
typedef __attribute__((ext_vector_type(4))) float f32x4;

__device__ __forceinline__ u16 f2bf(float f) {
  __bf16 h = (__bf16)f;
  return __builtin_bit_cast(u16, h);
}
__device__ __forceinline__ u32 pk2(float a, float b) {
  return (u32)f2bf(a) | ((u32)f2bf(b) << 16);
}
__device__ __forceinline__ float bf2f(u16 h) {
  return __uint_as_float(((u32)h) << 16);
}
__device__ __forceinline__ void gload16(const u16* g, u16* l) {
  __builtin_amdgcn_global_load_lds((const __attribute__((address_space(1))) void*)g,
                                   (__attribute__((address_space(3))) void*)l, 16, 0, 0);
}
__device__ __forceinline__ f32x4 mfma_bf16(bf16x8 a, bf16x8 b, f32x4 c) {
  return __builtin_amdgcn_mfma_f32_16x16x32_bf16(a, b, c, 0, 0, 0);
}

// ---------------- fp32 -> bf16 convert ----------------
__global__ __launch_bounds__(256) void cvt_bf16(const float* __restrict__ in,
                                                u16* __restrict__ out, int n8) {
  int i = blockIdx.x * 256 + threadIdx.x;
  int stride = gridDim.x * 256;
  for (; i < n8; i += stride) {
    float4 a = ((const float4*)in)[(size_t)i * 2];
    float4 b = ((const float4*)in)[(size_t)i * 2 + 1];
    ((uint4*)out)[i] = make_uint4(pk2(a.x, a.y), pk2(a.z, a.w), pk2(b.x, b.y), pk2(b.z, b.w));
  }
}

// ---------------- RMSNorm (H=2048), fp32 in -> bf16 out ----------------
__global__ __launch_bounds__(256) void rmsnorm_bf16(const float* __restrict__ x,
                                                    const float* __restrict__ g,
                                                    u16* __restrict__ o) {
  const int row = blockIdx.x;
  const int tid = threadIdx.x;
  const float4* xr = (const float4*)(x + (size_t)row * 2048);
  float4 a = xr[tid * 2], b = xr[tid * 2 + 1];
  float s = a.x * a.x + a.y * a.y + a.z * a.z + a.w * a.w +
            b.x * b.x + b.y * b.y + b.z * b.z + b.w * b.w;
#pragma unroll
  for (int off = 1; off < 64; off <<= 1) s += __shfl_xor(s, off);
  __shared__ float red[4];
  if ((tid & 63) == 0) red[tid >> 6] = s;
  __syncthreads();
  s = red[0] + red[1] + red[2] + red[3];
  const float r = rsqrtf(s * (1.0f / 2048.0f) + 1.1920929e-07f);
  const float4* gr = (const float4*)g;
  float4 ga = gr[tid * 2], gb = gr[tid * 2 + 1];
  ((uint4*)(o + (size_t)row * 2048))[tid] =
      make_uint4(pk2(a.x * r * ga.x, a.y * r * ga.y), pk2(a.z * r * ga.z, a.w * r * ga.w),
                 pk2(b.x * r * gb.x, b.y * r * gb.y), pk2(b.z * r * gb.z, b.w * r * gb.w));
}

// ========== fused gate+up GEMM: 256x128 tile, 4 phases, ONE barrier/phase ==========
// Out = silu(A@Wg^T) * (A@Wu^T), bf16. 16x16x32 MFMA, XOR window swizzle (verified
// conflict-free), vmcnt(4) counted prefetch. Measured R11: 269us, MfmaUtil 46.5%.
__global__ __launch_bounds__(512, 2) void gemmGU(const u16* __restrict__ A,
                                                 const u16* __restrict__ Bg,
                                                 const u16* __restrict__ Bu,
                                                 u16* __restrict__ Out,
                                                 int M, int N, int K) {
  alignas(16) __shared__ u16 lds[2 * 32768];
  const int tid = threadIdx.x;
  const int w = tid >> 6, lane = tid & 63;
  const int lo = lane & 15, hi = lane >> 4;
  // 2-D region-per-XCD swizzle
  const int nbm = M >> 8, nbx = N >> 7;
  const int RM = nbm >> 1, RN = nbx >> 2;
  const int xcd = blockIdx.x & 7, bidx = blockIdx.x >> 3;
  const int bm = ((xcd >> 2) * RM + bidx / RN) << 8;
  const int bn = ((xcd & 3) * RN + bidx % RN) << 7;
  const int wm = w >> 1, wn = w & 1;

  const int rw = (hi ^ ((lo >> 1) & 3)) * 8;  // read window within 32-u16 half-row
  const int arow0 = wm * 64 + lo, brow0 = wn * 64 + lo;

  const int srow = tid >> 2;                            // staged row within 128-slab
  const int scol = ((tid & 3) ^ ((tid >> 3) & 3)) * 8;  // inverse-swizzled source win
  const u16* Ab = A + (size_t)(bm + srow) * K + scol;
  const u16* Bgb = Bg + (size_t)(bn + srow) * K + scol;
  const u16* Bub = Bu + (size_t)(bn + srow) * K + scol;

  f32x4 gacc[4][4] = {}, uacc[4][4] = {};
  bf16x8 af[4], bf[4];

#define AOFF(par, kh) ((par)*32768 + (kh)*8192)
#define BGOFF(par, kh) ((par)*32768 + 16384 + (kh)*4096)
#define BUOFF(par, kh) ((par)*32768 + 24576 + (kh)*4096)
#define STG_A(par, kh, kt)                                                  \
  {                                                                         \
    gload16(Ab + (kt) + (kh)*32, &lds[AOFF(par, kh) + tid * 8]);            \
    gload16(Ab + (size_t)128 * K + (kt) + (kh)*32,                          \
            &lds[AOFF(par, kh) + 4096 + tid * 8]);                          \
  }
#define STG_B(par, kh, kt)                                                  \
  {                                                                         \
    gload16(Bgb + (kt) + (kh)*32, &lds[BGOFF(par, kh) + tid * 8]);          \
    gload16(Bub + (kt) + (kh)*32, &lds[BUOFF(par, kh) + tid * 8]);          \
  }
#define PHASE_SYNC()                                   \
  __builtin_amdgcn_s_barrier();                        \
  asm volatile("s_waitcnt lgkmcnt(0)" ::: "memory");   \
  __builtin_amdgcn_sched_barrier(0);
#define MFMA16(ACC)                                                         \
  __builtin_amdgcn_s_setprio(1);                                            \
  _Pragma("unroll") for (int m_ = 0; m_ < 4; ++m_)                          \
      _Pragma("unroll") for (int n_ = 0; n_ < 4; ++n_)                      \
          ACC[m_][n_] = mfma_bf16(af[m_], bf[n_], ACC[m_][n_]);             \
  __builtin_amdgcn_s_setprio(0);

  STG_A(0, 0, 0); STG_B(0, 0, 0); STG_A(0, 1, 0); STG_B(0, 1, 0);
  asm volatile("s_waitcnt vmcnt(0)" ::: "memory");
  __builtin_amdgcn_s_barrier();

  const int NT = K >> 6;
  for (int t = 0; t < NT; ++t) {
    const int par = t & 1, np = par ^ 1;
    const int ktn = (t + 1) << 6;
    const bool pre = (t + 1 < NT);

    // P0: kh0, gate
#pragma unroll
    for (int n = 0; n < 4; ++n)
      bf[n] = *(const bf16x8*)(&lds[BGOFF(par, 0)] + (brow0 + n * 16) * 32 + rw);
#pragma unroll
    for (int m = 0; m < 4; ++m)
      af[m] = *(const bf16x8*)(&lds[AOFF(par, 0)] + (arow0 + m * 16) * 32 + rw);
    if (pre) STG_A(np, 0, ktn);
    PHASE_SYNC();
    MFMA16(gacc);

    // P1: kh0, up (af reused)
#pragma unroll
    for (int n = 0; n < 4; ++n)
      bf[n] = *(const bf16x8*)(&lds[BUOFF(par, 0)] + (brow0 + n * 16) * 32 + rw);
    if (pre) STG_B(np, 0, ktn);
    if (pre) { asm volatile("s_waitcnt vmcnt(4)" ::: "memory"); }
    else     { asm volatile("s_waitcnt vmcnt(0)" ::: "memory"); }
    PHASE_SYNC();
    MFMA16(uacc);

    // P2: kh1, gate
#pragma unroll
    for (int n = 0; n < 4; ++n)
      bf[n] = *(const bf16x8*)(&lds[BGOFF(par, 1)] + (brow0 + n * 16) * 32 + rw);
#pragma unroll
    for (int m = 0; m < 4; ++m)
      af[m] = *(const bf16x8*)(&lds[AOFF(par, 1)] + (arow0 + m * 16) * 32 + rw);
    if (pre) STG_A(np, 1, ktn);
    PHASE_SYNC();
    MFMA16(gacc);

    // P3: kh1, up
#pragma unroll
    for (int n = 0; n < 4; ++n)
      bf[n] = *(const bf16x8*)(&lds[BUOFF(par, 1)] + (brow0 + n * 16) * 32 + rw);
    if (pre) STG_B(np, 1, ktn);
    if (pre) { asm volatile("s_waitcnt vmcnt(4)" ::: "memory"); }
    PHASE_SYNC();
    MFMA16(uacc);
  }
#undef AOFF
#undef BGOFF
#undef BUOFF
#undef STG_A
#undef STG_B
#undef PHASE_SYNC
#undef MFMA16

#pragma unroll
  for (int m = 0; m < 4; ++m) {
    const int gr = bm + wm * 64 + m * 16 + hi * 4;
#pragma unroll
    for (int n = 0; n < 4; ++n) {
      const int gc = bn + wn * 64 + n * 16 + lo;
#pragma unroll
      for (int r = 0; r < 4; ++r) {
        float g = gacc[m][n][r];
        float s = g / (1.f + __expf(-g));
        Out[(size_t)(gr + r) * N + gc] = f2bf(s * uacc[m][n][r]);
      }
    }
  }
}

// ========== 3-deep-pipelined 256x128 GEMM (QKV / O / down / unfused tier) ==========
template <int EPI>
__global__ __launch_bounds__(512, 1) void gemm3b(const u16* __restrict__ A,
                                                 const u16* __restrict__ B,
                                                 u16* Cb, float* Cf,
                                                 const float* __restrict__ Res,
                                                 int M, int N, int K, int lda) {
  constexpr int BUF = 24576;
  alignas(16) __shared__ u16 lds[3 * BUF];
  const int tid = threadIdx.x;
  const int w = tid >> 6, lane = tid & 63;
  const int lo = lane & 15, hi = lane >> 4;

  const int nbm = M >> 8, nbx = N >> 7;
  const int RM = nbm >> 1, RN = nbx >> 2;
  const int xcd = blockIdx.x & 7, idx = blockIdx.x >> 3;
  const int bm = ((xcd >> 2) * RM + idx / RN) << 8;
  const int bn = ((xcd & 3) * RN + idx % RN) << 7;

  const int wm = w >> 1, wn = w & 1;
  const int scol = ((tid & 7) ^ ((tid >> 3) & 7)) * 8;
  const u16* Ag = A + (size_t)(bm + (tid >> 3)) * lda + scol;
  const u16* Bg = B + (size_t)(bn + (tid >> 3)) * K + scol;

  f32x4 acc[4][4] = {};

#define STG(b, kt)                                                                    \
  {                                                                                   \
    _Pragma("unroll") for (int c = 0; c < 4; ++c)                                     \
        gload16(Ag + (size_t)(c * 64) * lda + (kt), &lds[(b)*BUF + c * 4096 + tid * 8]); \
    _Pragma("unroll") for (int c = 0; c < 2; ++c)                                     \
        gload16(Bg + (size_t)(c * 64) * K + (kt), &lds[(b)*BUF + 16384 + c * 4096 + tid * 8]); \
  }

  const int NT = K >> 6;
  STG(0, 0);
  STG(1, 64);

  int cur = 0;
  for (int T = 0; T < NT; ++T) {
    if (T + 1 < NT) {
      asm volatile("s_waitcnt vmcnt(6)" ::: "memory");
    } else {
      asm volatile("s_waitcnt vmcnt(0)" ::: "memory");
    }
    __builtin_amdgcn_s_barrier();
    __builtin_amdgcn_sched_barrier(0);

    const u16* LA = &lds[cur * BUF];
    const u16* LB = LA + 16384;
    bf16x8 af[4][2], bf[4][2];
#pragma unroll
    for (int ks = 0; ks < 2; ++ks) {
#pragma unroll
      for (int m = 0; m < 4; ++m)
        af[m][ks] = *(const bf16x8*)(LA + (wm * 64 + m * 16 + lo) * 64 +
                                     ((ks * 4 + hi) ^ (lo & 7)) * 8);
#pragma unroll
      for (int n = 0; n < 4; ++n)
        bf[n][ks] = *(const bf16x8*)(LB + (wn * 64 + n * 16 + lo) * 64 +
                                     ((ks * 4 + hi) ^ (lo & 7)) * 8);
    }
    if (T + 2 < NT) {
      const int nb = (cur + 2) % 3;
      STG(nb, (T + 2) << 6);
    }
    __builtin_amdgcn_s_setprio(1);
#pragma unroll
    for (int ks = 0; ks < 2; ++ks)
#pragma unroll
      for (int m = 0; m < 4; ++m)
#pragma unroll
        for (int n = 0; n < 4; ++n) acc[m][n] = mfma_bf16(af[m][ks], bf[n][ks], acc[m][n]);
    __builtin_amdgcn_s_setprio(0);
    cur = (cur + 1) % 3;
  }
#undef STG

#pragma unroll
  for (int m = 0; m < 4; ++m) {
    const int gr = bm + wm * 64 + m * 16 + hi * 4;
#pragma unroll
    for (int n = 0; n < 4; ++n) {
      const int gc = bn + wn * 64 + n * 16 + lo;
#pragma unroll
      for (int r = 0; r < 4; ++r) {
        const size_t idx2 = (size_t)(gr + r) * N + gc;
        if constexpr (EPI == 1) {
          Cf[idx2] = Res[idx2] + acc[m][n][r];
        } else if constexpr (EPI == 2) {
          float g = bf2f(Cb[idx2]);
          float s = g / (1.f + __expf(-g));
          Cb[idx2] = f2bf(s * acc[m][n][r]);
        } else {
          Cb[idx2] = f2bf(acc[m][n][r]);
        }
      }
    }
  }
}

// ---------------- old 128^2 GEMM (fallback tier), fp32 B on the fly ----------------
template <int EPI>
__global__ __launch_bounds__(256) void gemm_bt(const u16* __restrict__ A,
                                               const float* __restrict__ B,
                                               u16* Cb, float* Cf, const float* Res,
                                               int M, int N, int K) {
  alignas(16) __shared__ u16 As[128 * 32];
  alignas(16) __shared__ u16 Bs[128 * 32];
  const int tid = threadIdx.x;
  const int w = tid >> 6, lane = tid & 63;
  const int lo = lane & 15, hi = lane >> 4;
  const int bm = blockIdx.y * 128, bn = blockIdx.x * 128;
  const int wr = (w >> 1) * 64, wc = (w & 1) * 64;
  f32x4 acc[4][4] = {};
  const int r0 = tid >> 2, kc0 = (tid & 3) * 8;
  const u16* a0 = A + (size_t)(bm + r0) * K + kc0;
  const u16* a1 = A + (size_t)(bm + 64 + r0) * K + kc0;
  const float* b0 = B + (size_t)(bn + r0) * K + kc0;
  const float* b1 = B + (size_t)(bn + 64 + r0) * K + kc0;
  u16* asd0 = &As[(size_t)tid * 8];
  u16* asd1 = &As[(size_t)(tid + 256) * 8];
  u16* bsd0 = &Bs[(size_t)tid * 8];
  u16* bsd1 = &Bs[(size_t)(tid + 256) * 8];
  for (int kt = 0; kt < K; kt += 32) {
    gload16(a0 + kt, asd0);
    gload16(a1 + kt, asd1);
    float4 x0 = *(const float4*)(b0 + kt);
    float4 x1 = *(const float4*)(b0 + kt + 4);
    float4 y0 = *(const float4*)(b1 + kt);
    float4 y1 = *(const float4*)(b1 + kt + 4);
    *(uint4*)bsd0 = make_uint4(pk2(x0.x, x0.y), pk2(x0.z, x0.w), pk2(x1.x, x1.y), pk2(x1.z, x1.w));
    *(uint4*)bsd1 = make_uint4(pk2(y0.x, y0.y), pk2(y0.z, y0.w), pk2(y1.x, y1.y), pk2(y1.z, y1.w));
    __syncthreads();
    bf16x8 af[4], bfr[4];
#pragma unroll
    for (int i = 0; i < 4; ++i) {
      af[i] = *(const bf16x8*)(&As[(wr + i * 16 + lo) * 32 + hi * 8]);
      bfr[i] = *(const bf16x8*)(&Bs[(wc + i * 16 + lo) * 32 + hi * 8]);
    }
#pragma unroll
    for (int i = 0; i < 4; ++i)
#pragma unroll
      for (int j = 0; j < 4; ++j) acc[i][j] = mfma_bf16(af[i], bfr[j], acc[i][j]);
    __syncthreads();
  }
#pragma unroll
  for (int i = 0; i < 4; ++i) {
    const int gr = bm + wr + i * 16 + hi * 4;
#pragma unroll
    for (int j = 0; j < 4; ++j) {
      const int gc = bn + wc + j * 16 + lo;
#pragma unroll
      for (int r = 0; r < 4; ++r) {
        const size_t idx = (size_t)(gr + r) * N + gc;
        if constexpr (EPI == 1) {
          Cf[idx] = Res[idx] + acc[i][j][r];
        } else if constexpr (EPI == 2) {
          float g = bf2f(Cb[idx]);
          float s = g / (1.f + __expf(-g));
          Cb[idx] = f2bf(s * acc[i][j][r]);
        } else {
          Cb[idx] = f2bf(acc[i][j][r]);
        }
      }
    }
  }
}

// ---------------- V transpose: v rows (stride ldv) -> vt[bh*128+d][S] ----------------
__global__ __launch_bounds__(256) void transpose_v(const u16* __restrict__ v,
                                                   u16* __restrict__ vt, int ldv) {
  __shared__ u16 t[32][33];
  const int bh = blockIdx.z, b = bh >> 4, h = bh & 15;
  const int s0 = blockIdx.x * 32, d0 = blockIdx.y * 32;
  const int tx = threadIdx.x, ty = threadIdx.y;
#pragma unroll
  for (int i = 0; i < 4; ++i)
    t[ty + i * 8][tx] = v[(size_t)(b * 2048 + s0 + ty + i * 8) * ldv + h * 128 + d0 + tx];
  __syncthreads();
#pragma unroll
  for (int i = 0; i < 4; ++i)
    vt[(size_t)(bh * 128 + d0 + ty + i * 8) * 2048 + s0 + tx] = t[tx][ty + i * 8];
}

// ---------------- flash attention fwd: 512 thr, 128 q-rows/block, NO-MAX softmax ----------------
// 8 waves share each staged K/V tile. o may alias q.
__global__ __launch_bounds__(512) void attn_fwd3(const u16* __restrict__ q,
                                                 const u16* __restrict__ k,
                                                 const u16* __restrict__ vt,
                                                 u16* o, int ldq) {
  constexpr int S = 2048;
  alignas(16) __shared__ u16 Ks[2][64 * 128];
  alignas(16) __shared__ u16 Vs[2][128 * 64];
  alignas(16) __shared__ u16 plds[8][16 * 68];
  const int bh = blockIdx.y, b = bh >> 4, h = bh & 15;
  const int tid = threadIdx.x, w = tid >> 6, lane = tid & 63;
  const int lo = lane & 15, hi = lane >> 4;
  const int qr = blockIdx.x * 128 + w * 16;
  u16* pl = &plds[w][0];

  bf16x8 qf[4];
  const u16* qb = q + (size_t)(b * S + qr + lo) * ldq + h * 128 + hi * 8;
#pragma unroll
  for (int ks = 0; ks < 4; ++ks) qf[ks] = *(const bf16x8*)(qb + ks * 32);

  f32x4 oacc[8] = {};
  f32x4 lp = {0.f, 0.f, 0.f, 0.f};

  const u16* kb = k + (size_t)(b * S) * ldq + h * 128;
  const u16* vb = vt + (size_t)bh * 128 * S;

  const int kcs = ((tid & 15) ^ ((tid >> 4) & 7)) * 8;
  const int vcs = ((tid & 7) ^ ((tid >> 3) & 7)) * 8;
  const u16* kgs = kb + (size_t)(tid >> 4) * ldq + kcs;
  const u16* vgs = vb + (size_t)(tid >> 3) * S + vcs;

  int cur = 0;
#pragma unroll
  for (int c = 0; c < 2; ++c) gload16(kgs + (size_t)(c * 32) * ldq, &Ks[0][c * 4096 + tid * 8]);
#pragma unroll
  for (int c = 0; c < 2; ++c) gload16(vgs + (size_t)(c * 64) * S, &Vs[0][c * 4096 + tid * 8]);
  __syncthreads();

  const int swq = (lo & 7) << 4;
  constexpr float SCL = 0.12752956f;  // (1/sqrt(128)) * log2(e)

  for (int kv = 0; kv < S; kv += 64) {
    if (kv + 64 < S) {
      const int nb = cur ^ 1;
#pragma unroll
      for (int c = 0; c < 2; ++c)
        gload16(kgs + (size_t)(kv + 64 + c * 32) * ldq, &Ks[nb][c * 4096 + tid * 8]);
#pragma unroll
      for (int c = 0; c < 2; ++c)
        gload16(vgs + (size_t)(c * 64) * S + kv + 64, &Vs[nb][c * 4096 + tid * 8]);
    }
    const u16* Kc = &Ks[cur][0];
    const u16* Vc = &Vs[cur][0];

    f32x4 sacc[4] = {};
    __builtin_amdgcn_s_setprio(1);
#pragma unroll
    for (int ks = 0; ks < 4; ++ks)
#pragma unroll
      for (int n = 0; n < 4; ++n) {
        bf16x8 kf = *(const bf16x8*)(Kc + (n * 16 + lo) * 128 + (((ks * 64 + hi * 16) ^ swq) >> 1));
        sacc[n] = mfma_bf16(qf[ks], kf, sacc[n]);
      }
    __builtin_amdgcn_s_setprio(0);

    f32x4 p[4];
#pragma unroll
    for (int n = 0; n < 4; ++n)
#pragma unroll
      for (int r = 0; r < 4; ++r) p[n][r] = exp2f(sacc[n][r] * SCL);
#pragma unroll
    for (int r = 0; r < 4; ++r)
      lp[r] += (p[0][r] + p[1][r]) + (p[2][r] + p[3][r]);

#pragma unroll
    for (int n = 0; n < 4; ++n)
#pragma unroll
      for (int r = 0; r < 4; ++r)
        pl[(hi * 4 + r) * 68 + n * 16 + lo] = f2bf(p[n][r]);
    asm volatile("s_waitcnt lgkmcnt(0)" ::: "memory");
    bf16x8 pf0 = *(const bf16x8*)(pl + lo * 68 + hi * 8);
    bf16x8 pf1 = *(const bf16x8*)(pl + lo * 68 + 32 + hi * 8);

    __builtin_amdgcn_s_setprio(1);
#pragma unroll
    for (int f = 0; f < 8; ++f) {
      const int row = f * 16 + lo;
      bf16x8 vf0 = *(const bf16x8*)(Vc + row * 64 + (((hi * 16) ^ swq) >> 1));
      bf16x8 vf1 = *(const bf16x8*)(Vc + row * 64 + (((64 + hi * 16) ^ swq) >> 1));
      oacc[f] = mfma_bf16(pf0, vf0, oacc[f]);
      oacc[f] = mfma_bf16(pf1, vf1, oacc[f]);
    }
    __builtin_amdgcn_s_setprio(0);

    __syncthreads();
    cur ^= 1;
  }

  float l[4];
#pragma unroll
  for (int r = 0; r < 4; ++r) l[r] = lp[r];
#pragma unroll
  for (int off = 1; off < 16; off <<= 1)
#pragma unroll
    for (int r = 0; r < 4; ++r) l[r] += __shfl_xor(l[r], off);

  u16* ob = o + (size_t)(b * S + qr) * ldq + h * 128;
#pragma unroll
  for (int f = 0; f < 8; ++f)
#pragma unroll
    for (int r = 0; r < 4; ++r)
      ob[(size_t)(hi * 4 + r) * ldq + f * 16 + lo] = f2bf(oacc[f][r] / l[r]);
}

// ---------------- host ----------------
extern "C" void kernel_launch(void* const* d_in, const int* in_sizes, int n_in,
                              void* d_out, int out_size, void* d_ws, size_t ws_size,
                              hipStream_t stream) {
  constexpr int B = 2, S = 2048, H = 2048, NH = 16, I = 8192;
  constexpr int M = B * S;  // 4096

  const float* hs = (const float*)d_in[0];
  const float* Wq = (const float*)d_in[1];
  const float* Wk = (const float*)d_in[2];
  const float* Wv = (const float*)d_in[3];
  const float* Wo = (const float*)d_in[4];
  const float* Wg = (const float*)d_in[5];
  const float* Wu = (const float*)d_in[6];
  const float* Wd = (const float*)d_in[7];
  const float* g_in = (const float*)d_in[8];
  const float* g_post = (const float*)d_in[9];
  float* out = (float*)d_out;

  constexpr size_t SZ_HH = (size_t)H * H * 2;   // 8 MiB
  constexpr size_t SZ_IH = (size_t)I * H * 2;   // 32 MiB
  constexpr size_t SZ_MH = (size_t)M * H * 2;   // 16 MiB
  constexpr size_t NEED_BASE = SZ_MH + 3 * SZ_MH + SZ_MH + SZ_IH;   // 112 MiB
  constexpr size_t NEED_FUSED = NEED_BASE + SZ_IH;                  // 144 MiB

  if (ws_size >= NEED_BASE) {
    char* p = (char*)d_ws;
    u16* x_b = (u16*)p;    p += SZ_MH;      // [4096][2048]
    u16* qkv_b = (u16*)p;  p += 3 * SZ_MH;  // [4096][6144]
    u16* vt_b = (u16*)p;   p += SZ_MH;      // [B*NH*128][2048]
    u16* wsc = (u16*)p;    p += SZ_IH;      // weight scratch 32 MiB
    u16* gate_b = qkv_b;                    // [4096][8192] overlay after attn
    const bool fused = ws_size >= NEED_FUSED;
    u16* wu_b = fused ? (u16*)p : nullptr;  // 32 MiB (fused tier only)

    rmsnorm_bf16<<<M, 256, 0, stream>>>(hs, g_in, x_b);

    cvt_bf16<<<1024, 256, 0, stream>>>(Wq, wsc, H * H / 8);
    cvt_bf16<<<1024, 256, 0, stream>>>(Wk, wsc + (size_t)H * H, H * H / 8);
    cvt_bf16<<<1024, 256, 0, stream>>>(Wv, wsc + (size_t)2 * H * H, H * H / 8);
    gemm3b<0><<<(M / 256) * (3 * H / 128), 512, 0, stream>>>(
        x_b, wsc, qkv_b, nullptr, nullptr, M, 3 * H, H, H);

    transpose_v<<<dim3(S / 32, 128 / 32, B * NH), dim3(32, 8), 0, stream>>>(
        qkv_b + 2 * H, vt_b, 3 * H);
    attn_fwd3<<<dim3(S / 128, B * NH), 512, 0, stream>>>(qkv_b, qkv_b + H, vt_b, qkv_b, 3 * H);

    cvt_bf16<<<1024, 256, 0, stream>>>(Wo, wsc, H * H / 8);
    gemm3b<1><<<(M / 256) * (H / 128), 512, 0, stream>>>(
        qkv_b, wsc, nullptr, out, hs, M, H, H, 3 * H);

    rmsnorm_bf16<<<M, 256, 0, stream>>>(out, g_post, x_b);

    if (fused) {
      cvt_bf16<<<1024, 256, 0, stream>>>(Wg, wsc, I * H / 8);
      cvt_bf16<<<1024, 256, 0, stream>>>(Wu, wu_b, I * H / 8);
      gemmGU<<<(M / 256) * (I / 128), 512, 0, stream>>>(x_b, wsc, wu_b, gate_b, M, I, H);
    } else {
      cvt_bf16<<<1024, 256, 0, stream>>>(Wg, wsc, I * H / 8);
      gemm3b<0><<<(M / 256) * (I / 128), 512, 0, stream>>>(
          x_b, wsc, gate_b, nullptr, nullptr, M, I, H, H);
      cvt_bf16<<<1024, 256, 0, stream>>>(Wu, wsc, I * H / 8);
      gemm3b<2><<<(M / 256) * (I / 128), 512, 0, stream>>>(
          x_b, wsc, gate_b, nullptr, nullptr, M, I, H, H);
    }
    cvt_bf16<<<1024, 256, 0, stream>>>(Wd, wsc, I * H / 8);
    gemm3b<1><<<(M / 256) * (H / 128), 512, 0, stream>>>(
        gate_b, wsc, nullptr, out, out, M, H, I, I);
    return;
  }

  // ---------- fallback tier: old 128^2 path, fp32 B on the fly ----------
  constexpr int MC = 2048;
  char* p = (char*)d_ws;
  u16* x_b = (u16*)p;   p += SZ_MH;
  u16* q_b = (u16*)p;   p += SZ_MH;
  u16* k_b = (u16*)p;   p += SZ_MH;
  u16* v_b = (u16*)p;   p += SZ_MH;
  u16* vt_b = (u16*)p;  p += SZ_MH;
  u16* g_mlp = k_b;

  rmsnorm_bf16<<<M, 256, 0, stream>>>(hs, g_in, x_b);
  const dim3 gHH(H / 128, M / 128);
  gemm_bt<0><<<gHH, 256, 0, stream>>>(x_b, Wq, q_b, nullptr, nullptr, M, H, H);
  gemm_bt<0><<<gHH, 256, 0, stream>>>(x_b, Wk, k_b, nullptr, nullptr, M, H, H);
  gemm_bt<0><<<gHH, 256, 0, stream>>>(x_b, Wv, v_b, nullptr, nullptr, M, H, H);
  transpose_v<<<dim3(S / 32, 128 / 32, B * NH), dim3(32, 8), 0, stream>>>(v_b, vt_b, H);
  attn_fwd3<<<dim3(S / 128, B * NH), 512, 0, stream>>>(q_b, k_b, vt_b, q_b, H);
  gemm_bt<1><<<gHH, 256, 0, stream>>>(q_b, Wo, nullptr, out, hs, M, H, H);
  rmsnorm_bf16<<<M, 256, 0, stream>>>(out, g_post, x_b);
  const dim3 gIH(I / 128, MC / 128), gHI(H / 128, MC / 128);
  for (int mc = 0; mc < M / MC; ++mc) {
    const u16* xc = x_b + (size_t)mc * MC * H;
    float* oc = out + (size_t)mc * MC * H;
    gemm_bt<0><<<gIH, 256, 0, stream>>>(xc, Wg, g_mlp, nullptr, nullptr, MC, I, H);
    gemm_bt<2><<<gIH, 256, 0, stream>>>(xc, Wu, g_mlp, nullptr, nullptr, MC, I, H);
    gemm_bt<1><<<gHI, 256, 0, stream>>>(g_mlp, Wd, nullptr, oc, oc, MC, H, I);
  }
}